// Round 13
// baseline (174.765 us; speedup 1.0000x reference)
//
#include <hip/hip_runtime.h>
#include <stdint.h>

// BERT lattice embedding: ragged segment mean-pool.
// hidden: [B,S,H] f32, word_ids: [B,S] i32 (non-decreasing per sample),
// out: [B,T,H] f32; out[b,t,:] = mean of hidden[b,s,:] over s with
// word_ids[b,s]==t (zeros if no piece maps to t).
//
// v14: row-balanced wave partition. v10 (best, pool ~48us) assigned 4
// WORDS/wave -> span tail (binomial: 2..16 rows/wave) sets the one-shot
// makespan, and word-rounding reads +17% overshoot. v14 assigns ~8 ROWS
// per wave, snapped to word boundaries (no word split, fp order intact):
//  - Kernel A also computes P[b][k] = first word t with L[t] >= 8k
//    (64 waves/sample, exactly-8-row targets).
//  - Each wave streams its ~8-row contiguous range with v10's proven
//    2-row nt bursts; ONE rolling accumulator trio; word bounds come from
//    a preloaded register broadcast via __shfl (no in-loop dependent
//    loads). Empty words (incl. trailing) write zeros in the advance loop.
//  - Grid 1024 x 256 threads = exactly 4 blocks/CU (no quantization),
//    XCD-contiguous remap kept (128 blocks per XCD slab).
// v11 (4-row burst), v12 (sw pipeline), v13 (64-thr blocks) all regressed;
// their changes are NOT carried.

#define BB 64
#define SS 512
#define HH 768
#define TT 400
#define LN (TT + 1)        // bounds per sample (incl. sentinel L[400]=512)
#define NF4 (HH / 4)       // 192 float4 per row
#define NWS 64             // waves per sample
#define RPW (SS / NWS)     // target rows per wave = 8
#define BPS (NWS / 4)      // blocks per sample = 16 (4 waves/block)
#define NBLK (BB * BPS)    // 1024 blocks = 4 blocks/CU exactly
#define NXCD 8
#define BPX (NBLK / NXCD)  // 128 blocks per XCD slab
#define PN  (NWS + 1)      // partition entries per sample

typedef float f4 __attribute__((ext_vector_type(4)));

// ---- Kernel A: per-sample lower bounds + row-balanced word partition ----
__global__ __launch_bounds__(256) void bounds_kernel(
    const int* __restrict__ word_ids, int* __restrict__ L, int* __restrict__ P)
{
    const int b   = blockIdx.x;
    const int tid = threadIdx.x;

    __shared__ int s_w[SS];
    __shared__ int s_L[LN];

    const int2* r2 = reinterpret_cast<const int2*>(word_ids + b * SS);
    reinterpret_cast<int2*>(s_w)[tid] = r2[tid];          // 512 ints
    for (int t = tid; t < LN; t += 256) s_L[t] = SS;      // sentinel fill
    __syncthreads();

    // For each s: words t with w[s-1] < t <= w[s] have lower_bound(t) == s.
    // Ranges disjoint across s -> race-free LDS writes.
    for (int s = tid; s < SS; s += 256) {
        const int w  = s_w[s];
        const int wp = (s == 0) ? -1 : s_w[s - 1];
        for (int t = wp + 1; t <= w; ++t) s_L[t] = s;
    }
    __syncthreads();

    int* Lb = L + b * LN;
    for (int t = tid; t < LN; t += 256) Lb[t] = s_L[t];   // coalesced

    // Partition: P[k] = first word t (in [0,TT]) with L[t] >= k*RPW.
    // P[NWS] forced to TT so trailing empty words are owned by wave NWS-1.
    if (tid < NWS) {
        const int target = tid * RPW;
        int lo = 0, hi = TT;
        while (lo < hi) {
            const int m = (lo + hi) >> 1;
            if (s_L[m] < target) lo = m + 1; else hi = m;
        }
        P[b * PN + tid] = lo;
    }
    if (tid == NWS) P[b * PN + NWS] = TT;
}

// ---- Kernel B: row-balanced streaming pool ----
__global__ __launch_bounds__(256) void bert_lattice_pool_kernel(
    const float* __restrict__ hidden,
    const int* __restrict__ L,
    const int* __restrict__ P,
    float* __restrict__ out)
{
    const int p    = blockIdx.x;
    const int q    = (p % NXCD) * BPX + p / NXCD;   // xcd-contiguous remap
    const int b    = q / BPS;
    const int kin  = (q - b * BPS) * 4 + (threadIdx.x >> 6);  // wave 0..63
    const int lane = threadIdx.x & 63;

    const int* Lb = L + b * LN;
    const int* Pb = P + b * PN;
    const int P0 = Pb[kin];
    const int P1 = Pb[kin + 1];
    if (P0 >= P1) return;          // wave owns no words (giant-word neighbor)

    // Preload word bounds L[P0 + lane] into a register; broadcast via shfl.
    const int Lidx = (P0 + lane <= TT) ? P0 + lane : TT;
    const int Lreg = Lb[Lidx];

#define GETL(i)  ({ const int i_ = (i) <= TT ? (i) : TT;                   \
                    const int d_ = i_ - P0;                                \
                    (d_ < 64) ? __shfl(Lreg, d_) : Lb[i_]; })

    const int rbeg = GETL(P0);
    const int rend = GETL(P1);

    float* outp = out + (size_t)b * TT * HH;
    const f4 z4 = {0.f, 0.f, 0.f, 0.f};

#define ZWORD(tt) do {                                                     \
        f4* o_ = reinterpret_cast<f4*>(outp + (size_t)(tt) * HH) + lane;   \
        __builtin_nontemporal_store(z4, o_);                               \
        __builtin_nontemporal_store(z4, o_ + 64);                          \
        __builtin_nontemporal_store(z4, o_ + 128);                         \
    } while (0)

    int t  = P0;
    int ws = rbeg;          // current word's start row
    int e  = GETL(P0 + 1);  // current word's end row

    // Leading empty words.
    while (t < P1 && e == ws) { ZWORD(t); ++t; ws = e; e = GETL(t + 1); }

    f4 a0 = z4, a1 = z4, a2 = z4;

#define CLOSE() do {                                                       \
        const float inv = 1.0f / (float)(e - ws);                          \
        f4* o_ = reinterpret_cast<f4*>(outp + (size_t)t * HH) + lane;      \
        __builtin_nontemporal_store(a0 * inv, o_);                         \
        __builtin_nontemporal_store(a1 * inv, o_ + 64);                    \
        __builtin_nontemporal_store(a2 * inv, o_ + 128);                   \
        a0 = z4; a1 = z4; a2 = z4;                                         \
        ++t; ws = e; e = GETL(t + 1);                                      \
        while (t < P1 && e == ws) { ZWORD(t); ++t; ws = e; e = GETL(t + 1); } \
    } while (0)

    const f4* hp = reinterpret_cast<const f4*>(hidden)
                   + (size_t)(b * SS) * NF4 + lane;

    int s = rbeg;
    while (s < rend) {
        // Clamp to end of SAMPLE (valid memory); overshoot row is a real
        // neighbor row -> discarded value, same-XCD L2 warm-up.
        const int s1c = (s + 1 < SS) ? s + 1 : SS - 1;
        const f4* p0 = hp + (size_t)s   * NF4;
        const f4* p1 = hp + (size_t)s1c * NF4;
        // 6 independent nontemporal loads in one basic block (6 KB/wave).
        const f4 u0 = __builtin_nontemporal_load(p0);
        const f4 u1 = __builtin_nontemporal_load(p0 + 64);
        const f4 u2 = __builtin_nontemporal_load(p0 + 128);
        const f4 v0 = __builtin_nontemporal_load(p1);
        const f4 v1 = __builtin_nontemporal_load(p1 + 64);
        const f4 v2 = __builtin_nontemporal_load(p1 + 128);

        a0 += u0; a1 += u1; a2 += u2;
        if (s + 1 == e) CLOSE();
        if (s + 1 < rend) {
            a0 += v0; a1 += v1; a2 += v2;
            if (s + 2 == e) CLOSE();
        }
        s += 2;
    }
#undef CLOSE
#undef ZWORD
#undef GETL
}

extern "C" void kernel_launch(void* const* d_in, const int* in_sizes, int n_in,
                              void* d_out, int out_size, void* d_ws, size_t ws_size,
                              hipStream_t stream) {
    (void)in_sizes; (void)n_in; (void)ws_size; (void)out_size;
    const float* hidden   = (const float*)d_in[0];
    const int*   word_ids = (const int*)d_in[1];
    float*       out      = (float*)d_out;
    int*         L        = (int*)d_ws;            // BB*LN ints
    int*         P        = L + BB * LN;           // BB*PN ints

    bounds_kernel<<<dim3(BB), dim3(256), 0, stream>>>(word_ids, L, P);
    bert_lattice_pool_kernel<<<dim3(NBLK), dim3(256), 0, stream>>>(
        hidden, L, P, out);
}